// Round 2
// baseline (189.542 us; speedup 1.0000x reference)
//
#include <hip/hip_runtime.h>
#include <stdint.h>

#define NN 2048
#define DD 256
#define LL 4
#define DIN 128
#define DOUT 64
#define EE 65536
#define BM 4          // rows per block; NN/BM = 512 blocks -> 2 blocks/CU

// ---------------------------------------------------------------------------
// Established in rounds 0-7 (prev session):
// * Float tensors are f32 in AND out.
// * Attention contributes EXACTLY zero (multiplicative -1e6 mask -> softmax
//   underflow + post-mask zeroing; verified bit-identical in rounds 2/3).
// * Surviving computation (row-independent after deg):
//     h0 = x@Win + b_in + z[clip(deg,0,63)]
//     per layer l: xp = h + bo[l]; h = LN2(xp)@Wff[l] + bff[l] + xp
//     out = h@Wout + b_out
// Round 0 (this session): latency/barrier-convoy fix. 1024thr/grid256
// (1 block/CU, 28 barriers, 2-pass LN) -> 512thr/grid512 (2 independent
// barrier domains/CU, 16 barriers, 1-pass LN, h/xp register-resident,
// LDS 60.5KB->14.2KB). Round 1: resubmit unchanged — round-0 bench was an
// infra failure (container acquire), kernel audited clean for hangs/OOB.
// ---------------------------------------------------------------------------

__global__ __launch_bounds__(256) void k_deg(const int* __restrict__ ei, int* __restrict__ deg) {
    int t = blockIdx.x * 256 + threadIdx.x;
    if (t < EE) {
        unsigned v = (unsigned)ei[t];
        if (v < NN) atomicAdd(&deg[v], 1);
    }
}

__global__ __launch_bounds__(256) void k_fill(float* __restrict__ p, int n, float v) {
    int t = blockIdx.x * 256 + threadIdx.x;
    if (t < n) p[t] = v;
}

__global__ __launch_bounds__(512, 4) void k_mega(
        const float* __restrict__ x, const int* __restrict__ deg,
        const float* __restrict__ Win, const float* __restrict__ bin, const float* __restrict__ z,
        const float* __restrict__ bo, const float* __restrict__ lnw, const float* __restrict__ lnb,
        const float* __restrict__ Wff, const float* __restrict__ bff,
        const float* __restrict__ Wout, const float* __restrict__ bout,
        float* __restrict__ out) {
    const int n0 = blockIdx.x * BM;
    const int tid = threadIdx.x;
    const int c = tid >> 8;        // K-chunk 0..1
    const int d = tid & 255;       // column 0..255
    const int lane = tid & 63;
    const int wv = (tid >> 6) & 3; // wave within c-group
    const int r0 = 2 * c;          // this thread's row pair: r0, r0+1

    __shared__ float4 shnT[DD];        // LN rows transposed: shnT[k] = rows 0..3 at col k (4 KB)
    __shared__ float part[2][BM][DD];  // K-split partials (8 KB)
    __shared__ float4 xsT[DIN];        // x transposed (2 KB)
    __shared__ float2 red[BM][4];      // (sum, sumsq) cross-wave partials

    // ---- preload all per-layer params into registers (static index via
    //      unrolled layer loop); issue before first barrier to hide latency ----
    float pbo[LL], plw[LL], plb[LL], pbf[LL];
#pragma unroll
    for (int l = 0; l < LL; l++) {
        pbo[l] = bo[(size_t)l * DD + d];
        plw[l] = lnw[(size_t)l * DD + d];
        plb[l] = lnb[(size_t)l * DD + d];
        pbf[l] = bff[(size_t)l * DD + d];
    }
    float bi = bin[d];
    float zv[2];
    {
        int dg0 = deg[n0 + r0], dg1 = deg[n0 + r0 + 1];
        dg0 = dg0 < 0 ? 0 : (dg0 > 63 ? 63 : dg0);
        dg1 = dg1 < 0 ? 0 : (dg1 > 63 ? 63 : dg1);
        zv[0] = z[(size_t)dg0 * DD + d];
        zv[1] = z[(size_t)dg1 * DD + d];
    }
    // ---- stage x (transposed) ----
    {
        int rr = tid >> 7, kk = tid & 127;
        ((float*)&xsT[kk])[rr] = x[(size_t)(n0 + rr) * DIN + kk];
    }
    __syncthreads();

    // ---- h0 partials: k in [c*64, c*64+64) ----
    {
        float a0 = 0.f, a1 = 0.f, a2 = 0.f, a3 = 0.f;
        const float* W = Win + d;
#pragma unroll 4
        for (int k = c * 64; k < c * 64 + 64; k++) {
            float w = W[(size_t)k * DD];
            float4 a = xsT[k];
            a0 += a.x * w; a1 += a.y * w; a2 += a.z * w; a3 += a.w * w;
        }
        part[c][0][d] = a0; part[c][1][d] = a1; part[c][2][d] = a2; part[c][3][d] = a3;
    }
    __syncthreads();

    // h lives in registers across all layers (reader == writer thread mapping)
    float h[2];
#pragma unroll
    for (int i = 0; i < 2; i++) {
        int r = r0 + i;
        h[i] = part[0][r][d] + part[1][r][d] + bi + zv[i];
    }
    // part next written after two barriers (B1,B2) -> no extra barrier needed

    // ---- 4 fused layers, 3 barriers each ----
#pragma unroll
    for (int l = 0; l < LL; l++) {
        float xp0 = h[0] + pbo[l];
        float xp1 = h[1] + pbo[l];
        // one-pass LN stats for both rows, 4 interleaved shfl chains (ILP)
        float s0 = xp0, q0 = xp0 * xp0;
        float s1 = xp1, q1 = xp1 * xp1;
#pragma unroll
        for (int o = 32; o; o >>= 1) {
            s0 += __shfl_down(s0, o, 64);
            q0 += __shfl_down(q0, o, 64);
            s1 += __shfl_down(s1, o, 64);
            q1 += __shfl_down(q1, o, 64);
        }
        if (lane == 0) {
            red[r0][wv]     = make_float2(s0, q0);
            red[r0 + 1][wv] = make_float2(s1, q1);
        }
        __syncthreads();                       // B1
        {
            float2 e0 = red[r0][0], e1 = red[r0][1], e2 = red[r0][2], e3 = red[r0][3];
            float mu = (e0.x + e1.x + e2.x + e3.x) * (1.0f / 256.0f);
            float ms = (e0.y + e1.y + e2.y + e3.y) * (1.0f / 256.0f);
            float var = ms - mu * mu; var = var < 0.f ? 0.f : var;
            float inv = 1.0f / sqrtf(var + 1e-5f);
            ((float*)&shnT[d])[r0] = (xp0 - mu) * inv * plw[l] + plb[l];
        }
        {
            float2 e0 = red[r0 + 1][0], e1 = red[r0 + 1][1], e2 = red[r0 + 1][2], e3 = red[r0 + 1][3];
            float mu = (e0.x + e1.x + e2.x + e3.x) * (1.0f / 256.0f);
            float ms = (e0.y + e1.y + e2.y + e3.y) * (1.0f / 256.0f);
            float var = ms - mu * mu; var = var < 0.f ? 0.f : var;
            float inv = 1.0f / sqrtf(var + 1e-5f);
            ((float*)&shnT[d])[r0 + 1] = (xp1 - mu) * inv * plw[l] + plb[l];
        }
        __syncthreads();                       // B2

        // FF partials: k in [c*128, c*128+128)
        {
            float a0 = 0.f, a1 = 0.f, a2 = 0.f, a3 = 0.f;
            const float* W = Wff + (size_t)l * DD * DD + d;
#pragma unroll 4
            for (int k = c * 128; k < c * 128 + 128; k++) {
                float w = W[(size_t)k * DD];
                float4 a = shnT[k];            // b128 broadcast read
                a0 += a.x * w; a1 += a.y * w; a2 += a.z * w; a3 += a.w * w;
            }
            part[c][0][d] = a0; part[c][1][d] = a1; part[c][2][d] = a2; part[c][3][d] = a3;
        }
        __syncthreads();                       // B3
        h[0] = part[0][r0][d]     + part[1][r0][d]     + pbf[l] + xp0;
        h[1] = part[0][r0 + 1][d] + part[1][r0 + 1][d] + pbf[l] + xp1;
        // next red write is after all threads passed B3; next shnT write after
        // next B1; next part write after next B2 -> no 4th barrier needed
    }

    // ---- out = h@Wout + b_out (reuse shnT for transposed h) ----
#pragma unroll
    for (int i = 0; i < 2; i++) ((float*)&shnT[d])[r0 + i] = h[i];
    __syncthreads();
    {
        int sub = tid & 255;
        int r = sub >> 6, e = sub & 63;        // r uniform within a wave
        float a = 0.f;
        const float* W = Wout + e;
#pragma unroll 4
        for (int k = c * 128; k < c * 128 + 128; k++)
            a += ((const float*)&shnT[k])[r] * W[(size_t)k * DOUT];
        part[c][r][e] = a;
    }
    __syncthreads();
    if (tid < BM * DOUT) {
        int r = tid >> 6, e = tid & 63;
        out[(size_t)(n0 + r) * DOUT + e] = part[0][r][e] + part[1][r][e] + bout[e];
    }
}

// ---------------- host ----------------

extern "C" void kernel_launch(void* const* d_in, const int* in_sizes, int n_in,
                              void* d_out, int out_size, void* d_ws, size_t ws_size,
                              hipStream_t stream) {
    static const int expect[25] = {
        NN * DIN, 2 * EE, NN, 1000000, 2000000,
        DIN * DD, DD, 64 * DD, 10,
        LL * 8 * DD * DD, LL * 8 * DD, LL * 8 * DD * DD, LL * 8 * DD,
        LL * 8 * DD * DD, LL * 8 * DD, LL * 8 * DD * DD, LL * DD,
        LL * DD, LL * DD, LL * DD, LL * DD,
        LL * DD * DD, LL * DD, DD * DOUT, DOUT,
    };
    bool ok = (n_in == 25);
    if (ok)
        for (int i = 0; i < 25; i++)
            if (in_sizes[i] != expect[i]) { ok = false; break; }

    int* deg = (int*)d_ws;  // 8 KB
    if (!ok || ws_size < NN * sizeof(int) || out_size != NN * DOUT) {
        k_fill<<<(out_size + 255) / 256, 256, 0, stream>>>((float*)d_out, out_size, 100.0f);
        return;
    }

    const float* x = (const float*)d_in[0];
    const int* edge_index = (const int*)d_in[1];
    const float* Win = (const float*)d_in[5];
    const float* b_in = (const float*)d_in[6];
    const float* z = (const float*)d_in[7];
    const float* bo = (const float*)d_in[16];
    const float* ln2w = (const float*)d_in[19];
    const float* ln2b = (const float*)d_in[20];
    const float* Wff = (const float*)d_in[21];
    const float* bff = (const float*)d_in[22];
    const float* Wout = (const float*)d_in[23];
    const float* b_out = (const float*)d_in[24];

    hipMemsetAsync(deg, 0, NN * sizeof(int), stream);
    k_deg<<<EE / 256, 256, 0, stream>>>(edge_index, deg);
    k_mega<<<NN / BM, 512, 0, stream>>>(x, deg, Win, b_in, z, bo, ln2w, ln2b,
                                        Wff, bff, Wout, b_out, (float*)d_out);
}

// Round 3
// 167.243 us; speedup vs baseline: 1.1333x; 1.1333x over previous
//
#include <hip/hip_runtime.h>
#include <stdint.h>

#define NN 2048
#define DD 256
#define LL 4
#define DIN 128
#define DOUT 64
#define EE 65536
#define BM 8          // rows per block; NN/BM = 256 blocks -> 1 block/CU (min W traffic)

// ---------------------------------------------------------------------------
// Established in rounds 0-7 (prev session) + rounds 0-2 (this session):
// * Float tensors are f32 in AND out.
// * Attention contributes EXACTLY zero (multiplicative -1e6 mask -> softmax
//   underflow + post-mask zeroing; verified bit-identical).
// * Surviving computation (row-independent after deg):
//     h0 = x@Win + b_in + z[clip(deg,0,63)]
//     per layer l: xp = h + bo[l]; h = LN2(xp)@Wff[l] + bff[l] + xp
//     out = h@Wout + b_out
// * R2 lesson: kernel is L2-LOAD-LATENCY bound (VALUBusy ~20% at 1.1% HBM).
//   Grid 512 doubled per-CU W traffic -> regression 63->71us. Per-block W
//   read (256KB/layer) is INVARIANT in BM, so grid must stay 256.
// * This round: grid 256 x 1024thr + 16-deep register prefetch on W streams
//   (16 loads in flight vs compiler's 4 -> load-bound time 3200->800cy/layer),
//   one-pass LN (HW-validated absmax 0.001953 in R2), register h/xp,
//   3 barriers/layer (15 total), rolled layer loop + param prefetch.
// ---------------------------------------------------------------------------

__global__ __launch_bounds__(256) void k_deg(const int* __restrict__ ei, int* __restrict__ deg) {
    int t = blockIdx.x * 256 + threadIdx.x;
    if (t < EE) {
        unsigned v = (unsigned)ei[t];
        if (v < NN) atomicAdd(&deg[v], 1);
    }
}

__global__ __launch_bounds__(256) void k_fill(float* __restrict__ p, int n, float v) {
    int t = blockIdx.x * 256 + threadIdx.x;
    if (t < n) p[t] = v;
}

__global__ __launch_bounds__(1024, 4) void k_mega(
        const float* __restrict__ x, const int* __restrict__ deg,
        const float* __restrict__ Win, const float* __restrict__ bin, const float* __restrict__ z,
        const float* __restrict__ bo, const float* __restrict__ lnw, const float* __restrict__ lnb,
        const float* __restrict__ Wff, const float* __restrict__ bff,
        const float* __restrict__ Wout, const float* __restrict__ bout,
        float* __restrict__ out) {
    const int n0 = blockIdx.x * BM;
    const int tid = threadIdx.x;
    const int c = tid >> 8;        // K-chunk 0..3
    const int d = tid & 255;       // output column 0..255
    const int lane = tid & 63;
    const int wv = (tid >> 6) & 3; // wave within c-group
    const int r0 = 2 * c;          // rows owned for LN/residual: r0, r0+1

    __shared__ float4 shnT[DD][2];     // LN rows transposed: col k -> rows 0..7 (8 KB)
    __shared__ float part[4][BM][DD];  // K-split partials (32 KB)
    __shared__ float4 xsT[DIN][2];     // x transposed (4 KB)
    __shared__ float2 red[BM][4];      // (sum, sumsq) cross-wave partials

    // ---- preloads (issued before first barrier) ----
    float bi = bin[d];
    float zv0, zv1;
    {
        int dg0 = deg[n0 + r0], dg1 = deg[n0 + r0 + 1];
        dg0 = dg0 < 0 ? 0 : (dg0 > 63 ? 63 : dg0);
        dg1 = dg1 < 0 ? 0 : (dg1 > 63 ? 63 : dg1);
        zv0 = z[(size_t)dg0 * DD + d];
        zv1 = z[(size_t)dg1 * DD + d];
    }
    // layer-0 params (later layers prefetched inside the loop)
    float pbo = bo[d], plw = lnw[d], plb = lnb[d], pbf = bff[d];

    // ---- stage x (transposed) ----
    {
        int rr = tid >> 7, kk = tid & 127;
        ((float*)xsT)[kk * 8 + rr] = x[(size_t)(n0 + rr) * DIN + kk];
    }
    __syncthreads();

    // ---- h0 partials: k in [c*32, c*32+32), 16-deep double-buffered prefetch ----
    {
        float acc[BM] = {};
        const float* W = Win + d;
        const int kb = c * 32;
        float wA[16], wB[16];
#pragma unroll
        for (int j = 0; j < 16; j++) wA[j] = W[(size_t)(kb + j) * DD];
#pragma unroll
        for (int g = 0; g < 2; g++) {
            if (g < 1) {
#pragma unroll
                for (int j = 0; j < 16; j++) wB[j] = W[(size_t)(kb + 16 + j) * DD];
            }
#pragma unroll
            for (int j = 0; j < 16; j++) {
                int k = kb + g * 16 + j;
                float4 a = xsT[k][0], b2 = xsT[k][1];
                float w = wA[j];
                acc[0] += a.x * w;  acc[1] += a.y * w;  acc[2] += a.z * w;  acc[3] += a.w * w;
                acc[4] += b2.x * w; acc[5] += b2.y * w; acc[6] += b2.z * w; acc[7] += b2.w * w;
            }
            if (g < 1) {
#pragma unroll
                for (int j = 0; j < 16; j++) wA[j] = wB[j];
            }
        }
#pragma unroll
        for (int r = 0; r < BM; r++) part[c][r][d] = acc[r];
    }
    __syncthreads();

    // h register-resident across layers (reader == writer thread mapping)
    float h0v = part[0][r0][d] + part[1][r0][d] + part[2][r0][d] + part[3][r0][d] + bi + zv0;
    float h1v = part[0][r0+1][d] + part[1][r0+1][d] + part[2][r0+1][d] + part[3][r0+1][d] + bi + zv1;

    // ---- 4 fused layers, 3 barriers each ----
    for (int l = 0; l < LL; l++) {
        // prefetch next layer's params (have a full layer of latency cover)
        int ln = (l + 1 < LL) ? l + 1 : l;
        float nbo = bo[(size_t)ln * DD + d];
        float nlw = lnw[(size_t)ln * DD + d];
        float nlb = lnb[(size_t)ln * DD + d];
        float nbf = bff[(size_t)ln * DD + d];

        float xp0 = h0v + pbo;
        float xp1 = h1v + pbo;
        // one-pass LN stats, 4 interleaved shfl chains
        float s0 = xp0, q0 = xp0 * xp0;
        float s1 = xp1, q1 = xp1 * xp1;
#pragma unroll
        for (int o = 32; o; o >>= 1) {
            s0 += __shfl_down(s0, o, 64);
            q0 += __shfl_down(q0, o, 64);
            s1 += __shfl_down(s1, o, 64);
            q1 += __shfl_down(q1, o, 64);
        }
        if (lane == 0) {
            red[r0][wv]     = make_float2(s0, q0);
            red[r0 + 1][wv] = make_float2(s1, q1);
        }
        __syncthreads();                       // B1
        {
            float2 e0 = red[r0][0], e1 = red[r0][1], e2 = red[r0][2], e3 = red[r0][3];
            float mu = (e0.x + e1.x + e2.x + e3.x) * (1.0f / 256.0f);
            float ms = (e0.y + e1.y + e2.y + e3.y) * (1.0f / 256.0f);
            float var = ms - mu * mu; var = var < 0.f ? 0.f : var;
            float inv = 1.0f / sqrtf(var + 1e-5f);
            ((float*)shnT)[d * 8 + r0] = (xp0 - mu) * inv * plw + plb;
        }
        {
            float2 e0 = red[r0+1][0], e1 = red[r0+1][1], e2 = red[r0+1][2], e3 = red[r0+1][3];
            float mu = (e0.x + e1.x + e2.x + e3.x) * (1.0f / 256.0f);
            float ms = (e0.y + e1.y + e2.y + e3.y) * (1.0f / 256.0f);
            float var = ms - mu * mu; var = var < 0.f ? 0.f : var;
            float inv = 1.0f / sqrtf(var + 1e-5f);
            ((float*)shnT)[d * 8 + r0 + 1] = (xp1 - mu) * inv * plw + plb;
        }
        __syncthreads();                       // B2

        // FF partials: k in [c*64, c*64+64), 16-deep double-buffered prefetch
        {
            float acc[BM] = {};
            const float* W = Wff + (size_t)l * DD * DD + d;
            const int kb = c * 64;
            float wA[16], wB[16];
#pragma unroll
            for (int j = 0; j < 16; j++) wA[j] = W[(size_t)(kb + j) * DD];
#pragma unroll
            for (int g = 0; g < 4; g++) {
                if (g < 3) {
#pragma unroll
                    for (int j = 0; j < 16; j++) wB[j] = W[(size_t)(kb + (g + 1) * 16 + j) * DD];
                }
#pragma unroll
                for (int j = 0; j < 16; j++) {
                    int k = kb + g * 16 + j;
                    float4 a = shnT[k][0], b2 = shnT[k][1];   // b128 broadcast
                    float w = wA[j];
                    acc[0] += a.x * w;  acc[1] += a.y * w;  acc[2] += a.z * w;  acc[3] += a.w * w;
                    acc[4] += b2.x * w; acc[5] += b2.y * w; acc[6] += b2.z * w; acc[7] += b2.w * w;
                }
                if (g < 3) {
#pragma unroll
                    for (int j = 0; j < 16; j++) wA[j] = wB[j];
                }
            }
#pragma unroll
            for (int r = 0; r < BM; r++) part[c][r][d] = acc[r];
        }
        __syncthreads();                       // B3
        h0v = part[0][r0][d]   + part[1][r0][d]   + part[2][r0][d]   + part[3][r0][d]   + pbf + xp0;
        h1v = part[0][r0+1][d] + part[1][r0+1][d] + part[2][r0+1][d] + part[3][r0+1][d] + pbf + xp1;
        pbo = nbo; plw = nlw; plb = nlb; pbf = nbf;
        // hazards: red re-written after next B1's producers (post-B3); shnT
        // re-written after next B1; part re-written after next B2 -> safe.
    }

    // ---- out = h@Wout + b_out (reuse shnT for transposed h) ----
    ((float*)shnT)[d * 8 + r0]     = h0v;
    ((float*)shnT)[d * 8 + r0 + 1] = h1v;
    __syncthreads();
    {
        int r = tid >> 7;          // 0..7 (wave-uniform)
        int sub = tid & 127;
        int e = sub & 63;
        int hf = sub >> 6;         // 0..1 (wave-uniform)
        const float* W = Wout + e;
        const int kb = hf * 128;
        float a = 0.f;
        float wA[16], wB[16];
#pragma unroll
        for (int j = 0; j < 16; j++) wA[j] = W[(size_t)(kb + j) * DOUT];
#pragma unroll
        for (int g = 0; g < 8; g++) {
            if (g < 7) {
#pragma unroll
                for (int j = 0; j < 16; j++) wB[j] = W[(size_t)(kb + (g + 1) * 16 + j) * DOUT];
            }
#pragma unroll
            for (int j = 0; j < 16; j++)
                a += ((const float*)shnT)[(kb + g * 16 + j) * 8 + r] * wA[j];
            if (g < 7) {
#pragma unroll
                for (int j = 0; j < 16; j++) wA[j] = wB[j];
            }
        }
        part[hf][r][e] = a;
    }
    __syncthreads();
    if (tid < BM * DOUT) {
        int r = tid >> 6, e = tid & 63;
        out[(size_t)(n0 + r) * DOUT + e] = part[0][r][e] + part[1][r][e] + bout[e];
    }
}

// ---------------- host ----------------

extern "C" void kernel_launch(void* const* d_in, const int* in_sizes, int n_in,
                              void* d_out, int out_size, void* d_ws, size_t ws_size,
                              hipStream_t stream) {
    static const int expect[25] = {
        NN * DIN, 2 * EE, NN, 1000000, 2000000,
        DIN * DD, DD, 64 * DD, 10,
        LL * 8 * DD * DD, LL * 8 * DD, LL * 8 * DD * DD, LL * 8 * DD,
        LL * 8 * DD * DD, LL * 8 * DD, LL * 8 * DD * DD, LL * DD,
        LL * DD, LL * DD, LL * DD, LL * DD,
        LL * DD * DD, LL * DD, DD * DOUT, DOUT,
    };
    bool ok = (n_in == 25);
    if (ok)
        for (int i = 0; i < 25; i++)
            if (in_sizes[i] != expect[i]) { ok = false; break; }

    int* deg = (int*)d_ws;  // 8 KB
    if (!ok || ws_size < NN * sizeof(int) || out_size != NN * DOUT) {
        k_fill<<<(out_size + 255) / 256, 256, 0, stream>>>((float*)d_out, out_size, 100.0f);
        return;
    }

    const float* x = (const float*)d_in[0];
    const int* edge_index = (const int*)d_in[1];
    const float* Win = (const float*)d_in[5];
    const float* b_in = (const float*)d_in[6];
    const float* z = (const float*)d_in[7];
    const float* bo = (const float*)d_in[16];
    const float* ln2w = (const float*)d_in[19];
    const float* ln2b = (const float*)d_in[20];
    const float* Wff = (const float*)d_in[21];
    const float* bff = (const float*)d_in[22];
    const float* Wout = (const float*)d_in[23];
    const float* b_out = (const float*)d_in[24];

    hipMemsetAsync(deg, 0, NN * sizeof(int), stream);
    k_deg<<<EE / 256, 256, 0, stream>>>(edge_index, deg);
    k_mega<<<NN / BM, 1024, 0, stream>>>(x, deg, Win, b_in, z, bo, ln2w, ln2b,
                                         Wff, bff, Wout, b_out, (float*)d_out);
}